// Round 1
// baseline (82.989 us; speedup 1.0000x reference)
//
#include <hip/hip_runtime.h>
#include <math.h>

// Problem constants (DigitCapsules)
#define B_   64
#define IC   32
#define D_   288   // ICH*WID*HEI = 8*6*6
#define OC   10
#define OCH  16
#define J_   160   // OC*OCH
#define BJ   10240 // B_*J_

// ws layout (floats):
//   US   [0,      327680)  : [ic=32][b*160+j]
//   UDp  [327680, 332800)  : [block=512][o=10] partial u_dot
//   nacc [332800, 332803)  : n accumulator per routing iteration (zero-init by K1)
//   UD   [332816, 333136)  : udv[i*10+o]... stored as UD[tid] with i=tid&31,o=tid>>5
//   css  [333136, 333156)  : cs0[o] at +0, cs1[o] at +10
//   S2   [333184, 343424)  : s of final iteration (pre-squash)

// K1: u_sum[ic][b*160+j] = sum_d u[b,ic,d] * W[ic,d,j]
// grid 512 = bt(16) x ic(32, MINOR -> XCD = blockIdx%8 = ic%8: all 16 blocks
// sharing an ic slice of W land on the SAME XCD; W fetched once per XCD-L2).
// block 320 = dh(2) x b_sub(4) x j4(40). Also zero-inits nacc.
__global__ __launch_bounds__(320) void k_usum(const float* __restrict__ u,
                                              const float* __restrict__ Wt,
                                              float* __restrict__ US,
                                              float* __restrict__ UDp,
                                              float* __restrict__ nacc) {
    const int ic  = blockIdx.x & 31;
    const int bt  = blockIdx.x >> 5;    // 0..15
    const int tid = threadIdx.x;
    __shared__ float u_lds[4 * D_];     // [b_sub][d]
    __shared__ float part[640];         // dh=1 partials: [b_sub*40+j4] x float4
    __shared__ float ud_part[OC];
    if (tid < OC) ud_part[tid] = 0.f;
    if (blockIdx.x == 0 && tid == 0) {
        nacc[0] = 0.f; nacc[1] = 0.f; nacc[2] = 0.f;
    }
    // stage u: 4 rows x 288 floats = 288 float4, coalesced
    for (int idx = tid; idx < 288; idx += 320) {
        int b_sub = idx / 72;
        int f4    = idx - b_sub * 72;
        int b     = bt * 4 + b_sub;
        ((float4*)u_lds)[idx] =
            ((const float4*)(u + (size_t)(b * IC + ic) * D_))[f4];
    }
    __syncthreads();
    const int j4    = tid % 40;         // float4 index over j (lane-consecutive)
    const int b_sub = (tid / 40) & 3;
    const int dh    = tid / 160;        // d-half: 0 or 1
    const float4* wp = (const float4*)(Wt + (size_t)ic * D_ * J_)
                       + (size_t)dh * 144 * 40 + j4;
    const float*  ur = u_lds + b_sub * D_ + dh * 144;
    float ax = 0.f, ay = 0.f, az = 0.f, aw = 0.f;
    for (int d0 = 0; d0 < 144; d0 += 8) {
        float4 w0 = wp[(d0 + 0) * 40];
        float4 w1 = wp[(d0 + 1) * 40];
        float4 w2 = wp[(d0 + 2) * 40];
        float4 w3 = wp[(d0 + 3) * 40];
        float4 w4 = wp[(d0 + 4) * 40];
        float4 w5 = wp[(d0 + 5) * 40];
        float4 w6 = wp[(d0 + 6) * 40];
        float4 w7 = wp[(d0 + 7) * 40];
        float u0 = ur[d0 + 0], u1 = ur[d0 + 1], u2 = ur[d0 + 2], u3 = ur[d0 + 3];
        float u4 = ur[d0 + 4], u5 = ur[d0 + 5], u6 = ur[d0 + 6], u7 = ur[d0 + 7];
        ax += u0 * w0.x; ay += u0 * w0.y; az += u0 * w0.z; aw += u0 * w0.w;
        ax += u1 * w1.x; ay += u1 * w1.y; az += u1 * w1.z; aw += u1 * w1.w;
        ax += u2 * w2.x; ay += u2 * w2.y; az += u2 * w2.z; aw += u2 * w2.w;
        ax += u3 * w3.x; ay += u3 * w3.y; az += u3 * w3.z; aw += u3 * w3.w;
        ax += u4 * w4.x; ay += u4 * w4.y; az += u4 * w4.z; aw += u4 * w4.w;
        ax += u5 * w5.x; ay += u5 * w5.y; az += u5 * w5.z; aw += u5 * w5.w;
        ax += u6 * w6.x; ay += u6 * w6.y; az += u6 * w6.z; aw += u6 * w6.w;
        ax += u7 * w7.x; ay += u7 * w7.y; az += u7 * w7.z; aw += u7 * w7.w;
    }
    if (dh == 1) ((float4*)part)[tid - 160] = make_float4(ax, ay, az, aw);
    __syncthreads();
    if (dh == 0) {
        float4 p = ((float4*)part)[tid];
        ax += p.x; ay += p.y; az += p.z; aw += p.w;
        ((float4*)(US + (size_t)ic * BJ + (bt * 4 + b_sub) * J_))[j4] =
            make_float4(ax, ay, az, aw);
        // u_dot partial: thread's 4 j's share o = j4>>2; aligned 4-lane groups
        float g = ax + ay + az + aw;
        g += __shfl_xor(g, 1);
        g += __shfl_xor(g, 2);
        if ((tid & 3) == 0) atomicAdd(&ud_part[j4 >> 2], g);
    }
    __syncthreads();
    if (tid < OC) UDp[blockIdx.x * OC + tid] = ud_part[tid];
}

// K2: routing iteration 0. b_ij = 0 -> c = 1/32 uniform (exact), so no softmax
// and no cij needed: s0 = 2^-5 * sum_i US[i][t] (bit-identical to fmac with
// c=2^-5). Accumulates n0 into nacc[0]. Block 0 additionally reduces UDp ->
// UD[i][o] and stores cs0[o] = 2^-5 * sum_i udv. Kernel boundary = grid
// barrier: NO device-scope spin anywhere.
__global__ __launch_bounds__(320) void k_iter0(const float* __restrict__ US,
                                               const float* __restrict__ UDp,
                                               float* __restrict__ nacc,
                                               float* __restrict__ UD,
                                               float* __restrict__ css) {
    const int tid = threadIdx.x;
    const int t   = blockIdx.x * 320 + tid;
    __shared__ float wred[5];
    float s = 0.f;
    {
        const float* usp = US + t;
        #pragma unroll
        for (int ii = 0; ii < IC; ++ii) s += usp[(size_t)ii * BJ];
        s *= 0.03125f;   // exact (power of two)
    }
    float a = fabsf(s);
    #pragma unroll
    for (int off = 32; off; off >>= 1) a += __shfl_down(a, off);
    if ((tid & 63) == 0) wred[tid >> 6] = a;
    if (blockIdx.x == 0) {
        const int i = tid & 31;
        const int o = tid >> 5;
        float udv = 0.f;
        #pragma unroll
        for (int bt = 0; bt < 16; ++bt) udv += UDp[(bt * 32 + i) * OC + o];
        UD[tid] = udv;
        float cs = udv;
        cs += __shfl_xor(cs, 16, 32);
        cs += __shfl_xor(cs,  8, 32);
        cs += __shfl_xor(cs,  4, 32);
        cs += __shfl_xor(cs,  2, 32);
        cs += __shfl_xor(cs,  1, 32);
        if (i == 0) css[o] = cs * 0.03125f;
    }
    __syncthreads();
    if (tid == 0)
        atomicAdd(nacc + 0, wred[0] + wred[1] + wred[2] + wred[3] + wred[4]);
}

// K3: routing iteration 1. Rebuilds b1 = udv * f(n0) * cs0 (same op order as
// the fused version's bij update -> bit-identical), softmax over i, dot,
// accumulates n1, block 0 stores cs1[o].
__global__ __launch_bounds__(320) void k_iter1(const float* __restrict__ US,
                                               const float* __restrict__ UD,
                                               float* __restrict__ css,
                                               float* __restrict__ nacc) {
    const int tid = threadIdx.x;
    const int i   = tid & 31;
    const int o   = tid >> 5;
    const int t   = blockIdx.x * 320 + tid;
    __shared__ float cij[OC * IC];
    __shared__ float wred[5];
    const float udv = UD[tid];
    const float n0  = nacc[0];
    const float n02 = n0 * n0;
    float bij = udv * ((n02 / (1.f + n02)) * (css[o] / n0));
    // softmax over i (32 aligned lanes)
    float m = bij;
    m = fmaxf(m, __shfl_xor(m, 16, 32));
    m = fmaxf(m, __shfl_xor(m,  8, 32));
    m = fmaxf(m, __shfl_xor(m,  4, 32));
    m = fmaxf(m, __shfl_xor(m,  2, 32));
    m = fmaxf(m, __shfl_xor(m,  1, 32));
    float e  = __expf(bij - m);
    float se = e;
    se += __shfl_xor(se, 16, 32);
    se += __shfl_xor(se,  8, 32);
    se += __shfl_xor(se,  4, 32);
    se += __shfl_xor(se,  2, 32);
    se += __shfl_xor(se,  1, 32);
    float c = e / se;
    cij[o * IC + i] = c;
    float cs = c * udv;
    cs += __shfl_xor(cs, 16, 32);
    cs += __shfl_xor(cs,  8, 32);
    cs += __shfl_xor(cs,  4, 32);
    cs += __shfl_xor(cs,  2, 32);
    cs += __shfl_xor(cs,  1, 32);
    if (blockIdx.x == 0 && i == 0) css[10 + o] = cs;
    __syncthreads();                    // cij visible
    float s = 0.f;
    {
        const int ot = (t >> 4) % OC;
        const float* usp = US + t;
        const float* cp  = cij + ot * IC;
        #pragma unroll
        for (int ii = 0; ii < IC; ++ii) s += cp[ii] * usp[(size_t)ii * BJ];
    }
    float a = fabsf(s);
    #pragma unroll
    for (int off = 32; off; off >>= 1) a += __shfl_down(a, off);
    if ((tid & 63) == 0) wred[tid >> 6] = a;
    __syncthreads();
    if (tid == 0)
        atomicAdd(nacc + 1, wred[0] + wred[1] + wred[2] + wred[3] + wred[4]);
}

// K4: routing iteration 2. b2 = udv*f(n0)*cs0 + udv*f(n1)*cs1 (same op order),
// softmax, dot; stores raw s to S2 and accumulates n2. Squash finishes in K5
// (needs the GLOBAL n2, available only after this kernel completes).
__global__ __launch_bounds__(320) void k_iter2(const float* __restrict__ US,
                                               const float* __restrict__ UD,
                                               const float* __restrict__ css,
                                               float* __restrict__ nacc,
                                               float* __restrict__ S2) {
    const int tid = threadIdx.x;
    const int i   = tid & 31;
    const int o   = tid >> 5;
    const int t   = blockIdx.x * 320 + tid;
    __shared__ float cij[OC * IC];
    __shared__ float wred[5];
    const float udv = UD[tid];
    const float n0  = nacc[0];
    const float n1  = nacc[1];
    const float n02 = n0 * n0;
    const float n12 = n1 * n1;
    float bij = udv * ((n02 / (1.f + n02)) * (css[o] / n0));
    bij      += udv * ((n12 / (1.f + n12)) * (css[10 + o] / n1));
    float m = bij;
    m = fmaxf(m, __shfl_xor(m, 16, 32));
    m = fmaxf(m, __shfl_xor(m,  8, 32));
    m = fmaxf(m, __shfl_xor(m,  4, 32));
    m = fmaxf(m, __shfl_xor(m,  2, 32));
    m = fmaxf(m, __shfl_xor(m,  1, 32));
    float e  = __expf(bij - m);
    float se = e;
    se += __shfl_xor(se, 16, 32);
    se += __shfl_xor(se,  8, 32);
    se += __shfl_xor(se,  4, 32);
    se += __shfl_xor(se,  2, 32);
    se += __shfl_xor(se,  1, 32);
    cij[o * IC + i] = e / se;
    __syncthreads();
    float s = 0.f;
    {
        const int ot = (t >> 4) % OC;
        const float* usp = US + t;
        const float* cp  = cij + ot * IC;
        #pragma unroll
        for (int ii = 0; ii < IC; ++ii) s += cp[ii] * usp[(size_t)ii * BJ];
    }
    S2[t] = s;
    float a = fabsf(s);
    #pragma unroll
    for (int off = 32; off; off >>= 1) a += __shfl_down(a, off);
    if ((tid & 63) == 0) wred[tid >> 6] = a;
    __syncthreads();
    if (tid == 0)
        atomicAdd(nacc + 2, wred[0] + wred[1] + wred[2] + wred[3] + wred[4]);
}

// K5: squash of the final iteration. out[t] = (n2^2/(1+n2^2)) * (S2[t]/n2),
// same expression order as the fused version.
__global__ __launch_bounds__(1024) void k_out(const float* __restrict__ S2,
                                              const float* __restrict__ nacc,
                                              float* __restrict__ out) {
    const int t = blockIdx.x * 1024 + threadIdx.x;
    const float n  = nacc[2];
    const float n2 = n * n;
    out[t] = (n2 / (1.f + n2)) * (S2[t] / n);
}

extern "C" void kernel_launch(void* const* d_in, const int* in_sizes, int n_in,
                              void* d_out, int out_size, void* d_ws, size_t ws_size,
                              hipStream_t stream) {
    (void)in_sizes; (void)n_in; (void)out_size; (void)ws_size;
    const float* u  = (const float*)d_in[0];
    const float* Wt = (const float*)d_in[1];
    float* ws   = (float*)d_ws;
    float* US   = ws;               // 327680 floats: [ic=32][b*160+j]
    float* UDp  = ws + 327680;      // 5120 floats: [block=512][o=10]
    float* nacc = ws + 332800;      // 3 floats
    float* UD   = ws + 332816;      // 320 floats: udv[(i,o)]
    float* css  = ws + 333136;      // 20 floats: cs0[o], cs1[o]
    float* S2   = ws + 333184;      // 10240 floats: final-iteration s

    // 5 dispatches; every inter-iteration global sync is a kernel boundary
    // (stream order), not a device-scope spin. K1 zero-inits nacc (ws is
    // poisoned 0xAA each launch).
    k_usum <<<dim3(512), dim3(320),  0, stream>>>(u, Wt, US, UDp, nacc);
    k_iter0<<<dim3(32),  dim3(320),  0, stream>>>(US, UDp, nacc, UD, css);
    k_iter1<<<dim3(32),  dim3(320),  0, stream>>>(US, UD, css, nacc);
    k_iter2<<<dim3(32),  dim3(320),  0, stream>>>(US, UD, css, nacc, S2);
    k_out  <<<dim3(10),  dim3(1024), 0, stream>>>(S2, nacc, (float*)d_out);
}